// Round 1
// baseline (337.985 us; speedup 1.0000x reference)
//
#include <hip/hip_runtime.h>
#include <stdint.h>

#define NCOLS 8192
#define BS    256
#define NB    16
#define NT    64
#define TILES 4   // column tiles per workgroup; gridx = NCOLS/(NT*TILES) = 32

typedef float    f32x4  __attribute__((ext_vector_type(4)));
typedef short    bf16x8 __attribute__((ext_vector_type(8)));
typedef unsigned u32x4  __attribute__((ext_vector_type(4)));

// RNE-pack two fp32 into one dword of two bf16 (lo = first arg)
__device__ __forceinline__ unsigned pack2(float lo, float hi) {
  unsigned a = __builtin_bit_cast(unsigned, lo);
  unsigned b = __builtin_bit_cast(unsigned, hi);
  a += 0x7FFFu + ((a >> 16) & 1u);
  b += 0x7FFFu + ((b >> 16) & 1u);
  return (a >> 16) | (b & 0xFFFF0000u);
}

// Convert W (16x256x256 fp32) -> bf16 in ws. 8 elems/thread.
__global__ __launch_bounds__(256) void wcvt_kernel(const float* __restrict__ Wf,
                                                   unsigned* __restrict__ Wb) {
  int i = blockIdx.x * 256 + threadIdx.x;
  f32x4 a = ((const f32x4*)Wf)[2 * i];
  f32x4 c = ((const f32x4*)Wf)[2 * i + 1];
  u32x4 o;
  o.x = pack2(a.x, a.y); o.y = pack2(a.z, a.w);
  o.z = pack2(c.x, c.y); o.w = pack2(c.z, c.w);
  ((u32x4*)Wb)[i] = o;
}

// wg: block b (M=256) x a strip of TILES=4 column tiles (NT=64 each).
// Double-buffered LDS X-stage; loads for tile t+1 are issued right after
// packing tile t so HBM reads stay in flight under compute+epilogue of t.
// Buffer reuse at tile t+2 is fenced by the two barriers of tile t+1.
template<bool USE_WS>
__global__ __launch_bounds__(256, 2)
void bg_kernel(const float* __restrict__ X, const float* __restrict__ Wf,
               const unsigned short* __restrict__ Wb, float* __restrict__ out) {
  __shared__ unsigned xs[2][NT * 128];  // two 32 KiB [n][kd] XOR-swizzled buffers
  const int b    = blockIdx.y;
  const int s0   = blockIdx.x * (NT * TILES);
  const int t    = threadIdx.x;
  const int wid  = t >> 6;
  const int lane = t & 63;
  const int sub  = lane & 3;
  const int cg   = lane >> 2;
  const int krow = wid * 8 + sub * 2;
  const int ln16 = lane & 15;
  const int quad = lane >> 4;

  const float* xb0 = X + (size_t)b * BS * NCOLS + s0 + 4 * cg;

  f32x4 st[16];
  auto stage_load = [&](int tt) {
    const float* xb = xb0 + tt * NT;
#pragma unroll
    for (int p = 0; p < 8; ++p) {
      const int k0 = p * 32 + krow;
      st[2 * p]     = *(const f32x4*)(xb + (size_t)k0 * NCOLS);
      st[2 * p + 1] = *(const f32x4*)(xb + (size_t)(k0 + 1) * NCOLS);
    }
  };
  auto stage_pack = [&](unsigned* buf) {
#pragma unroll
    for (int p = 0; p < 8; ++p) {
      const int kd = (p * 32 + krow) >> 1;
#pragma unroll
      for (int j = 0; j < 4; ++j) {
        const int n = 4 * cg + j;
        const int f = (n ^ (n >> 2)) & 7;
        buf[n * 128 + (kd ^ (f << 2))] = pack2(st[2 * p][j], st[2 * p + 1][j]);
      }
    }
  };

  const size_t wbase = ((size_t)(b * BS + wid * 64 + ln16)) * BS + quad * 8;
  auto loadA = [&](int ks, int mt) -> bf16x8 {
    const size_t off = wbase + (size_t)(mt * 16) * BS + ks * 32;
    if (USE_WS) {
      return *(const bf16x8*)(Wb + off);
    } else {
      f32x4 w0 = *(const f32x4*)(Wf + off);
      f32x4 w1 = *(const f32x4*)(Wf + off + 4);
      union { unsigned u[4]; bf16x8 v; } cv;
      cv.u[0] = pack2(w0.x, w0.y); cv.u[1] = pack2(w0.z, w0.w);
      cv.u[2] = pack2(w1.x, w1.y); cv.u[3] = pack2(w1.z, w1.w);
      return cv.v;
    }
  };

  stage_load(0);

  for (int tt = 0; tt < TILES; ++tt) {
    unsigned* buf = xs[tt & 1];
    stage_pack(buf);                       // counted vmcnt wait on st only
    if (tt + 1 < TILES) stage_load(tt + 1);  // next tile's HBM reads in flight
    __syncthreads();                       // buf ready for all waves

    auto loadB = [&](int ks, int nt) -> bf16x8 {
      const int n = nt * 16 + ln16;
      const int f = (n ^ (n >> 2)) & 7;
      return *(const bf16x8*)(&buf[n * 128 + ((ks * 16 + quad * 4) ^ (f << 2))]);
    };

    f32x4 acc[4][4] = {};
    bf16x8 afr[2][4], bfr[2][4];
#pragma unroll
    for (int i = 0; i < 4; ++i) { afr[0][i] = loadA(0, i); bfr[0][i] = loadB(0, i); }

#pragma unroll
    for (int ks = 0; ks < 8; ++ks) {
      const int cur = ks & 1, nxt = cur ^ 1;
      if (ks < 7) {
#pragma unroll
        for (int i = 0; i < 4; ++i) { afr[nxt][i] = loadA(ks + 1, i); bfr[nxt][i] = loadB(ks + 1, i); }
      }
#pragma unroll
      for (int mt = 0; mt < 4; ++mt)
#pragma unroll
        for (int nt = 0; nt < 4; ++nt)
          acc[mt][nt] = __builtin_amdgcn_mfma_f32_16x16x32_bf16(afr[cur][mt], bfr[cur][nt],
                                                                acc[mt][nt], 0, 0, 0);
    }

    __syncthreads();  // all waves done reading buf; it becomes per-wave scratch

    // epilogue: transpose acc through buf (per-wave region, stride 68)
    const int c0 = s0 + tt * NT;
    float* lw = (float*)buf + wid * 1088;  // 16 rows x 68 floats = 4352 B/wave
    const int erow = lane >> 4;            // 0..3
    const int ecol = 4 * (lane & 15);      // 0..60
#pragma unroll
    for (int mt = 0; mt < 4; ++mt) {
#pragma unroll
      for (int r = 0; r < 4; ++r)
#pragma unroll
        for (int nt = 0; nt < 4; ++nt)
          lw[(quad * 4 + r) * 68 + nt * 16 + ln16] = acc[mt][nt][r];
      __asm__ volatile("s_waitcnt lgkmcnt(0)" ::: "memory");
#pragma unroll
      for (int j = 0; j < 4; ++j) {
        f32x4 v = *(const f32x4*)(lw + (j * 4 + erow) * 68 + ecol);
        *(f32x4*)(out + (size_t)(b * BS + wid * 64 + mt * 16 + j * 4 + erow) * NCOLS + c0 + ecol) = v;
      }
      __asm__ volatile("s_waitcnt lgkmcnt(0)" ::: "memory");
    }
  }
}

extern "C" void kernel_launch(void* const* d_in, const int* in_sizes, int n_in,
                              void* d_out, int out_size, void* d_ws, size_t ws_size,
                              hipStream_t stream) {
  const float* X  = (const float*)d_in[0];
  const float* Wf = (const float*)d_in[1];
  float* out      = (float*)d_out;
  dim3 grid(NCOLS / (NT * TILES), NB);
  const size_t wneed = (size_t)NB * BS * BS * sizeof(unsigned short);
  if (ws_size >= wneed) {
    unsigned* Wb = (unsigned*)d_ws;
    wcvt_kernel<<<dim3((NB * BS * BS) / (256 * 8)), 256, 0, stream>>>(Wf, Wb);
    bg_kernel<true><<<grid, 256, 0, stream>>>(X, Wf, (const unsigned short*)Wb, out);
  } else {
    bg_kernel<false><<<grid, 256, 0, stream>>>(X, Wf, nullptr, out);
  }
}

// Round 2
// 269.121 us; speedup vs baseline: 1.2559x; 1.2559x over previous
//
#include <hip/hip_runtime.h>
#include <stdint.h>

#define NCOLS 8192
#define BS    256
#define NB    16
#define NT    32   // col tile per wg; LDS 16 KiB -> up to 8 resident wgs/CU

typedef float    f32x4  __attribute__((ext_vector_type(4)));
typedef short    bf16x8 __attribute__((ext_vector_type(8)));
typedef unsigned u32x4  __attribute__((ext_vector_type(4)));

// RNE-pack two fp32 into one dword of two bf16 (lo = first arg)
__device__ __forceinline__ unsigned pack2(float lo, float hi) {
  unsigned a = __builtin_bit_cast(unsigned, lo);
  unsigned b = __builtin_bit_cast(unsigned, hi);
  a += 0x7FFFu + ((a >> 16) & 1u);
  b += 0x7FFFu + ((b >> 16) & 1u);
  return (a >> 16) | (b & 0xFFFF0000u);
}

// Convert W (16x256x256 fp32) -> bf16 in ws. 8 elems/thread.
__global__ __launch_bounds__(256) void wcvt_kernel(const float* __restrict__ Wf,
                                                   unsigned* __restrict__ Wb) {
  int i = blockIdx.x * 256 + threadIdx.x;
  f32x4 a = ((const f32x4*)Wf)[2 * i];
  f32x4 c = ((const f32x4*)Wf)[2 * i + 1];
  u32x4 o;
  o.x = pack2(a.x, a.y); o.y = pack2(a.z, a.w);
  o.z = pack2(c.x, c.y); o.w = pack2(c.z, c.w);
  ((u32x4*)Wb)[i] = o;
}

// wg: block b (M=256) x NT=32 cols. One tile per wg (round-0 structure);
// latency hiding comes from ~8 resident wgs/CU with staggered phases.
// X tile staged transposed+swizzled bf16 in 16 KiB LDS; W A-frags
// double-buffer-prefetched from L2-resident bf16 ws. Epilogue transposes
// acc through the dead xs buffer (per-wave region, stride 36).
template<bool USE_WS>
__global__ __launch_bounds__(256, 2)
void bg_kernel(const float* __restrict__ X, const float* __restrict__ Wf,
               const unsigned short* __restrict__ Wb, float* __restrict__ out) {
  __shared__ unsigned xs[NT * 128];  // [n][kd] dwords, XOR-swizzled, 16 KiB
  const int b    = blockIdx.y;
  const int c0   = blockIdx.x * NT;
  const int t    = threadIdx.x;
  const int wid  = t >> 6;
  const int lane = t & 63;
  const int cg   = lane & 7;    // col group: 8 x f32x4 = 32 floats/row
  const int sub  = lane >> 3;   // 8 row-subgroups
  const int ln16 = lane & 15;
  const int quad = lane >> 4;

  // ---- stage X tile: K=256 x NT=32, fp32 -> bf16, transpose to [n][k]
  {
    const float* xb = X + (size_t)b * BS * NCOLS + c0 + 4 * cg;
    f32x4 st[8];
#pragma unroll
    for (int p = 0; p < 4; ++p) {
      const int k0 = wid * 64 + p * 16 + sub * 2;  // each wave owns a 64-row band
      st[2 * p]     = *(const f32x4*)(xb + (size_t)k0 * NCOLS);
      st[2 * p + 1] = *(const f32x4*)(xb + (size_t)(k0 + 1) * NCOLS);
    }
#pragma unroll
    for (int p = 0; p < 4; ++p) {
      const int kd = wid * 32 + p * 8 + sub;  // (k0)>>1
#pragma unroll
      for (int j = 0; j < 4; ++j) {
        const int n = 4 * cg + j;
        const int f = (n ^ (n >> 2)) & 7;
        xs[n * 128 + (kd ^ (f << 2))] = pack2(st[2 * p][j], st[2 * p + 1][j]);
      }
    }
  }
  __syncthreads();

  // ---- compute with explicit 2-deep fragment pipeline
  const size_t wbase = ((size_t)(b * BS + wid * 64 + ln16)) * BS + quad * 8;

  auto loadA = [&](int ks, int mt) -> bf16x8 {
    const size_t off = wbase + (size_t)(mt * 16) * BS + ks * 32;
    if (USE_WS) {
      return *(const bf16x8*)(Wb + off);
    } else {
      f32x4 w0 = *(const f32x4*)(Wf + off);
      f32x4 w1 = *(const f32x4*)(Wf + off + 4);
      union { unsigned u[4]; bf16x8 v; } cv;
      cv.u[0] = pack2(w0.x, w0.y); cv.u[1] = pack2(w0.z, w0.w);
      cv.u[2] = pack2(w1.x, w1.y); cv.u[3] = pack2(w1.z, w1.w);
      return cv.v;
    }
  };
  auto loadB = [&](int ks, int nt) -> bf16x8 {
    const int n = nt * 16 + ln16;
    const int f = (n ^ (n >> 2)) & 7;
    return *(const bf16x8*)(&xs[n * 128 + ((ks * 16 + quad * 4) ^ (f << 2))]);
  };

  f32x4 acc[4][2] = {};
  bf16x8 afr[2][4], bfr[2][2];
#pragma unroll
  for (int i = 0; i < 4; ++i) afr[0][i] = loadA(0, i);
#pragma unroll
  for (int i = 0; i < 2; ++i) bfr[0][i] = loadB(0, i);

#pragma unroll
  for (int ks = 0; ks < 8; ++ks) {
    const int cur = ks & 1, nxt = cur ^ 1;
    if (ks < 7) {
#pragma unroll
      for (int i = 0; i < 4; ++i) afr[nxt][i] = loadA(ks + 1, i);
#pragma unroll
      for (int i = 0; i < 2; ++i) bfr[nxt][i] = loadB(ks + 1, i);
    }
#pragma unroll
    for (int mt = 0; mt < 4; ++mt)
#pragma unroll
      for (int nt = 0; nt < 2; ++nt)
        acc[mt][nt] = __builtin_amdgcn_mfma_f32_16x16x32_bf16(afr[cur][mt], bfr[cur][nt],
                                                              acc[mt][nt], 0, 0, 0);
  }

  // ---- epilogue: transpose acc through xs (per-wave region, stride 36)
  __syncthreads();  // all waves done reading xs
  float* lw = (float*)xs + wid * 576;   // 16 rows x 36 floats = 2304 B/wave
  const int erow = lane >> 3;           // 0..7
  const int ecol = 4 * (lane & 7);      // 0..28
#pragma unroll
  for (int mt = 0; mt < 4; ++mt) {
#pragma unroll
    for (int r = 0; r < 4; ++r)
#pragma unroll
      for (int nt = 0; nt < 2; ++nt)
        lw[(quad * 4 + r) * 36 + nt * 16 + ln16] = acc[mt][nt][r];
    __asm__ volatile("s_waitcnt lgkmcnt(0)" ::: "memory");
#pragma unroll
    for (int j = 0; j < 2; ++j) {
      f32x4 v = *(const f32x4*)(lw + (j * 8 + erow) * 36 + ecol);
      *(f32x4*)(out + (size_t)(b * BS + wid * 64 + mt * 16 + j * 8 + erow) * NCOLS + c0 + ecol) = v;
    }
    __asm__ volatile("s_waitcnt lgkmcnt(0)" ::: "memory");
  }
}

extern "C" void kernel_launch(void* const* d_in, const int* in_sizes, int n_in,
                              void* d_out, int out_size, void* d_ws, size_t ws_size,
                              hipStream_t stream) {
  const float* X  = (const float*)d_in[0];
  const float* Wf = (const float*)d_in[1];
  float* out      = (float*)d_out;
  dim3 grid(NCOLS / NT, NB);
  const size_t wneed = (size_t)NB * BS * BS * sizeof(unsigned short);
  if (ws_size >= wneed) {
    unsigned* Wb = (unsigned*)d_ws;
    wcvt_kernel<<<dim3((NB * BS * BS) / (256 * 8)), 256, 0, stream>>>(Wf, Wb);
    bg_kernel<true><<<grid, 256, 0, stream>>>(X, Wf, (const unsigned short*)Wb, out);
  } else {
    bg_kernel<false><<<grid, 256, 0, stream>>>(X, Wf, nullptr, out);
  }
}

// Round 3
// 252.850 us; speedup vs baseline: 1.3367x; 1.0644x over previous
//
#include <hip/hip_runtime.h>
#include <stdint.h>

#define NCOLS 8192
#define BS    256
#define NB    16
#define NT    32                 // cols per tile
#define STRIP 256                // cols per wg
#define NTILES (STRIP / NT)      // 8
#define GX    (NCOLS / STRIP)    // 32

typedef float    f32x4  __attribute__((ext_vector_type(4)));
typedef short    bf16x8 __attribute__((ext_vector_type(8)));
typedef unsigned u32x4  __attribute__((ext_vector_type(4)));

// RNE-pack two fp32 into one dword of two bf16 (lo = first arg)
__device__ __forceinline__ unsigned pack2(float lo, float hi) {
  unsigned a = __builtin_bit_cast(unsigned, lo);
  unsigned b = __builtin_bit_cast(unsigned, hi);
  a += 0x7FFFu + ((a >> 16) & 1u);
  b += 0x7FFFu + ((b >> 16) & 1u);
  return (a >> 16) | (b & 0xFFFF0000u);
}

// Convert W (16x256x256 fp32) -> bf16 in ws. 8 elems/thread.
__global__ __launch_bounds__(256) void wcvt_kernel(const float* __restrict__ Wf,
                                                   unsigned* __restrict__ Wb) {
  int i = blockIdx.x * 256 + threadIdx.x;
  f32x4 a = ((const f32x4*)Wf)[2 * i];
  f32x4 c = ((const f32x4*)Wf)[2 * i + 1];
  u32x4 o;
  o.x = pack2(a.x, a.y); o.y = pack2(a.z, a.w);
  o.z = pack2(c.x, c.y); o.w = pack2(c.z, c.w);
  ((u32x4*)Wb)[i] = o;
}

// Streaming wg: block b x STRIP=256 cols, looping over NTILES=8 tiles of NT=32.
// W band (64 rows x 256 K) lives in 128 VGPRs per wave. X staged fp32 linear in
// double-buffered LDS via global_load_lds (no staging regs). One raw barrier +
// counted vmcnt(8) per tile keeps next tile's HBM reads in flight under the
// whole compute of the current tile.
template<bool USE_WS>
__global__ __launch_bounds__(256, 2)
void bg_kernel(const float* __restrict__ X, const float* __restrict__ Wf,
               const unsigned short* __restrict__ Wb, float* __restrict__ out) {
  __shared__ float xsA[BS * NT];     // 32 KiB
  __shared__ float xsB[BS * NT];     // 32 KiB
  __shared__ float es[4 * 16 * 36];  // 9 KiB epilogue transpose scratch

  const int b     = blockIdx.y;
  const int cbase = blockIdx.x * STRIP;
  const int tid   = threadIdx.x;
  const int wid   = tid >> 6;
  const int lane  = tid & 63;
  const int ln16  = lane & 15;
  const int quad  = lane >> 4;
  const int srow  = lane >> 3;       // 0..7
  const int scol4 = (lane & 7) * 4;  // 0..28

  // ---- stage issue: 8 x global_load_lds(16B) per wave = 8 KiB (rows wid*64..+64)
  auto stage = [&](float* dstbuf, int t) {
    const float* src = X + ((size_t)(b * BS + wid * 64 + srow)) * NCOLS
                         + (cbase + t * NT) + scol4;
#pragma unroll
    for (int p = 0; p < 8; ++p) {
      __builtin_amdgcn_global_load_lds(
          (const __attribute__((address_space(1))) void*)(src + (size_t)(p * 8) * NCOLS),
          (__attribute__((address_space(3))) void*)(dstbuf + wid * 2048 + p * 256),
          16, 0, 0);
    }
  };

  // ---- W band into registers: wfr[ks][mt], all indexing compile-time (rule 20)
  bf16x8 wfr[8][4];
  {
    const size_t wb0 = ((size_t)(b * BS + wid * 64 + ln16)) * BS + quad * 8;
    if (USE_WS) {
#pragma unroll
      for (int ks = 0; ks < 8; ++ks)
#pragma unroll
        for (int mt = 0; mt < 4; ++mt)
          wfr[ks][mt] = *(const bf16x8*)(Wb + wb0 + (size_t)(mt * 16) * BS + ks * 32);
    } else {
#pragma unroll
      for (int ks = 0; ks < 8; ++ks)
#pragma unroll
        for (int mt = 0; mt < 4; ++mt) {
          const size_t off = wb0 + (size_t)(mt * 16) * BS + ks * 32;
          f32x4 w0 = *(const f32x4*)(Wf + off);
          f32x4 w1 = *(const f32x4*)(Wf + off + 4);
          union { unsigned u[4]; bf16x8 v; } cv;
          cv.u[0] = pack2(w0.x, w0.y); cv.u[1] = pack2(w0.z, w0.w);
          cv.u[2] = pack2(w1.x, w1.y); cv.u[3] = pack2(w1.z, w1.w);
          wfr[ks][mt] = cv.v;
        }
    }
  }

  // ---- prologue: tile 0 staged + W loaded, full drain once
  stage(xsA, 0);
  __builtin_amdgcn_sched_barrier(0);
  __asm__ volatile("s_waitcnt vmcnt(0)" ::: "memory");
  __builtin_amdgcn_s_barrier();
  __builtin_amdgcn_sched_barrier(0);

  float* cur = xsA;
  float* nxt = xsB;

#pragma unroll 1
  for (int t = 0; t < NTILES; ++t) {
    if (t + 1 < NTILES) {
      stage(nxt, t + 1);                    // 8 loads: oldest vmem ops this tile
      __builtin_amdgcn_sched_barrier(0);    // pin issue before any compute vmem
    }

    // ---- compute tile t from cur (fp32 linear [256][32])
    f32x4 acc[4][2] = {};
#pragma unroll
    for (int ks = 0; ks < 8; ++ks) {
      bf16x8 bfr[2];
#pragma unroll
      for (int nt = 0; nt < 2; ++nt) {
        const float* col = cur + (ks * 32 + quad * 8) * NT + nt * 16 + ln16;
        union { unsigned u[4]; bf16x8 v; } cv;
#pragma unroll
        for (int j = 0; j < 4; ++j)
          cv.u[j] = pack2(col[(2 * j) * NT], col[(2 * j + 1) * NT]);
        bfr[nt] = cv.v;
      }
#pragma unroll
      for (int mt = 0; mt < 4; ++mt)
#pragma unroll
        for (int nt = 0; nt < 2; ++nt)
          acc[mt][nt] = __builtin_amdgcn_mfma_f32_16x16x32_bf16(wfr[ks][mt], bfr[nt],
                                                                acc[mt][nt], 0, 0, 0);
    }

    // ---- epilogue: per-wave private LDS transpose -> 8 f32x4 stores
    {
      const int c0 = cbase + t * NT;
      float* lw = es + wid * 576;  // 16 rows x 36 floats
#pragma unroll
      for (int mt = 0; mt < 4; ++mt) {
#pragma unroll
        for (int r = 0; r < 4; ++r)
#pragma unroll
          for (int nt = 0; nt < 2; ++nt)
            lw[(quad * 4 + r) * 36 + nt * 16 + ln16] = acc[mt][nt][r];
        __asm__ volatile("s_waitcnt lgkmcnt(0)" ::: "memory");
#pragma unroll
        for (int j = 0; j < 2; ++j) {
          f32x4 v = *(const f32x4*)(lw + (j * 8 + srow) * 36 + scol4);
          *(f32x4*)(out + (size_t)(b * BS + wid * 64 + mt * 16 + j * 8 + srow) * NCOLS
                        + c0 + scol4) = v;
        }
        __asm__ volatile("s_waitcnt lgkmcnt(0)" ::: "memory");
      }
    }

    if (t + 1 < NTILES) {
      __builtin_amdgcn_sched_barrier(0);
      // outstanding (FIFO): 8 stage loads (oldest) + 8 epilogue stores.
      // vmcnt(8): stage loads complete, stores stay in flight. Never 0 in-loop.
      __asm__ volatile("s_waitcnt vmcnt(8)" ::: "memory");
      __builtin_amdgcn_s_barrier();
      __builtin_amdgcn_sched_barrier(0);
      float* tmp = cur; cur = nxt; nxt = tmp;
    }
  }
}

extern "C" void kernel_launch(void* const* d_in, const int* in_sizes, int n_in,
                              void* d_out, int out_size, void* d_ws, size_t ws_size,
                              hipStream_t stream) {
  const float* X  = (const float*)d_in[0];
  const float* Wf = (const float*)d_in[1];
  float* out      = (float*)d_out;
  dim3 grid(GX, NB);
  const size_t wneed = (size_t)NB * BS * BS * sizeof(unsigned short);
  if (ws_size >= wneed) {
    unsigned* Wb = (unsigned*)d_ws;
    wcvt_kernel<<<dim3((NB * BS * BS) / (256 * 8)), 256, 0, stream>>>(Wf, Wb);
    bg_kernel<true><<<grid, 256, 0, stream>>>(X, Wf, (const unsigned short*)Wb, out);
  } else {
    bg_kernel<false><<<grid, 256, 0, stream>>>(X, Wf, nullptr, out);
  }
}